// Round 1
// baseline (191.679 us; speedup 1.0000x reference)
//
#include <hip/hip_runtime.h>
#include <math.h>

// Problem constants
#define F_IN  256
#define NOUT  256          // N_HEADS * N_HIDDEN
#define NB    8            // batch
#define NN    1024         // nodes
#define NH    8            // heads
#define ND    32           // hidden per head
#define NROWS (NB * NN)    // 8192
#define LOG2E 1.44269504f

// ---------------------------------------------------------------------------
// Kernel 1: g = vertex @ w_vert  (8192x256 @ 256x256), fp32 tiled GEMM.
// Epilogue: s_src/s_dst = g . w_src / w_dst per (row, head), via shuffle-xor
// reduction across the 8 threads that own each head's 32 columns.
// Tile: 64x64 per WG, 256 threads, 4x4 micro-tile per thread, TK=16.
// ---------------------------------------------------------------------------
__global__ __launch_bounds__(256) void gat_gemm_kernel(
    const float* __restrict__ vertex, const float* __restrict__ w_vert,
    const float* __restrict__ attn_w, float* __restrict__ g,
    float* __restrict__ s_src, float* __restrict__ s_dst)
{
    // +4 pad: keeps 16B alignment for b128 ops and breaks write-bank aliasing
    __shared__ __align__(16) float a_lds[16][68];   // transposed: [k][row]
    __shared__ __align__(16) float b_lds[16][68];   // [k][col]

    const int tid = threadIdx.x;
    const int gc0 = blockIdx.x * 64;
    const int gr0 = blockIdx.y * 64;

    const int tr = tid >> 4;          // 0..15
    const int tc = tid & 15;          // 0..15
    const int r0 = tr * 4;
    const int c0 = tc * 4;

    // staging assignments
    const int arow = tid >> 2;        // 0..63
    const int akq  = (tid & 3) * 4;   // 0,4,8,12
    const int bk   = tid >> 4;        // 0..15
    const int bcq  = (tid & 15) * 4;  // 0..60

    float acc[4][4] = {};

    for (int k0 = 0; k0 < F_IN; k0 += 16) {
        float4 av = *(const float4*)&vertex[(size_t)(gr0 + arow) * F_IN + k0 + akq];
        a_lds[akq + 0][arow] = av.x;
        a_lds[akq + 1][arow] = av.y;
        a_lds[akq + 2][arow] = av.z;
        a_lds[akq + 3][arow] = av.w;
        *(float4*)&b_lds[bk][bcq] =
            *(const float4*)&w_vert[(size_t)(k0 + bk) * NOUT + gc0 + bcq];
        __syncthreads();

        #pragma unroll
        for (int kk = 0; kk < 16; ++kk) {
            float4 va = *(const float4*)&a_lds[kk][r0];
            float4 vb = *(const float4*)&b_lds[kk][c0];
            float af[4] = {va.x, va.y, va.z, va.w};
            float bf[4] = {vb.x, vb.y, vb.z, vb.w};
            #pragma unroll
            for (int ri = 0; ri < 4; ++ri)
                #pragma unroll
                for (int ci = 0; ci < 4; ++ci)
                    acc[ri][ci] += af[ri] * bf[ci];
        }
        __syncthreads();
    }

    // write g
    #pragma unroll
    for (int ri = 0; ri < 4; ++ri) {
        float4 o;
        o.x = acc[ri][0]; o.y = acc[ri][1]; o.z = acc[ri][2]; o.w = acc[ri][3];
        *(float4*)&g[(size_t)(gr0 + r0 + ri) * NOUT + gc0 + c0] = o;
    }

    // epilogue: per-(row, head) score dots. tc 0..7 -> head0 of this tile,
    // tc 8..15 -> head1. Reduce over tc&7 (lane bits 0..2) with shuffle-xor.
    const int dl = (tc & 7) * 4;   // d offset within head
    float ws0 = attn_w[dl + 0], ws1 = attn_w[dl + 1];
    float ws2 = attn_w[dl + 2], ws3 = attn_w[dl + 3];
    float wd0 = attn_w[ND + dl + 0], wd1 = attn_w[ND + dl + 1];
    float wd2 = attn_w[ND + dl + 2], wd3 = attn_w[ND + dl + 3];

    #pragma unroll
    for (int ri = 0; ri < 4; ++ri) {
        float ps = acc[ri][0] * ws0 + acc[ri][1] * ws1 +
                   acc[ri][2] * ws2 + acc[ri][3] * ws3;
        float pd = acc[ri][0] * wd0 + acc[ri][1] * wd1 +
                   acc[ri][2] * wd2 + acc[ri][3] * wd3;
        #pragma unroll
        for (int off = 1; off < 8; off <<= 1) {
            ps += __shfl_xor(ps, off);
            pd += __shfl_xor(pd, off);
        }
        if ((tc & 7) == 0) {
            const int row = gr0 + r0 + ri;
            const int gh  = (gc0 >> 5) + (tc >> 3);
            s_src[row * NH + gh] = ps;
            s_dst[row * NH + gh] = pd;
        }
    }
}

// ---------------------------------------------------------------------------
// Kernel 2: out[b,i,h,:] = sum_j softmax_j(lrelu(s_src[i]+s_dst[j])) g[b,j,h,:]
// One WG per (b, h, 128-row i-block). 512 WGs, 256 threads.
// Phase 1: exact m_i, 1/l_i per row (scores are rank-structured -> cheap).
// Phase 2: 64-j chunks: stage g-chunk + normalized p-chunk in LDS, then
// GEMM-style accumulation with 4i x 4d micro-tiles.
// ---------------------------------------------------------------------------
__global__ __launch_bounds__(256) void gat_attn_kernel(
    const float* __restrict__ g, const float* __restrict__ s_src,
    const float* __restrict__ s_dst, float* __restrict__ out)
{
    __shared__ __align__(16) float sd[NN];        // s_dst row for (b,h): 4 KB
    __shared__ __align__(16) float ss[128];       // s_src for my i-block
    __shared__ __align__(16) float mk[128];       // m_i * log2e
    __shared__ __align__(16) float rr[128];       // 1 / l_i
    __shared__ __align__(16) float gj[64][32];    // g chunk: 8 KB
    __shared__ __align__(16) float pj[64][128];   // p chunk [j][i]: 32 KB

    const int b  = blockIdx.z;
    const int h  = blockIdx.y;
    const int i0 = blockIdx.x * 128;
    const int t  = threadIdx.x;

    // ---- phase 0: load score vectors ----
    #pragma unroll
    for (int q = 0; q < 4; ++q) {
        const int j = t + 256 * q;
        sd[j] = s_dst[(size_t)(b * NN + j) * NH + h];
    }
    if (t < 128) ss[t] = s_src[(size_t)(b * NN + i0 + t) * NH + h];
    __syncthreads();

    // ---- phase 1: per-row max + denom (exact, no online rescale) ----
    const int lane = t & 63;
    const int w    = t >> 6;
    float sdr[16];
    #pragma unroll
    for (int q = 0; q < 16; ++q) sdr[q] = sd[lane + 64 * q];

    for (int k = 0; k < 32; ++k) {
        const int il = w * 32 + k;
        const float si = ss[il];
        float ev[16];
        float m = -3.0e38f;
        #pragma unroll
        for (int q = 0; q < 16; ++q) {
            float x = si + sdr[q];
            x = fmaxf(x, 0.2f * x);          // leaky relu
            ev[q] = x;
            m = fmaxf(m, x);
        }
        #pragma unroll
        for (int off = 32; off >= 1; off >>= 1)
            m = fmaxf(m, __shfl_xor(m, off));
        float s = 0.f;
        #pragma unroll
        for (int q = 0; q < 16; ++q)
            s += exp2f((ev[q] - m) * LOG2E);
        #pragma unroll
        for (int off = 32; off >= 1; off >>= 1)
            s += __shfl_xor(s, off);
        if (lane == 0) { mk[il] = m * LOG2E; rr[il] = 1.0f / s; }
    }
    __syncthreads();

    // ---- phase 2: j-chunks of 64 ----
    const int ti = t >> 3;     // 0..31 -> i micro-row * 4
    const int td = t & 7;      // 0..7  -> d micro-col * 4
    float acc[4][4] = {};

    for (int jc = 0; jc < NN; jc += 64) {
        if (jc) __syncthreads();   // previous chunk's 2c done before restage

        // 2a: stage g chunk (64 x 32)
        #pragma unroll
        for (int q = 0; q < 2; ++q) {
            const int f  = t + 256 * q;      // 0..511
            const int jj = f >> 3;
            const int dq = (f & 7) * 4;
            *(float4*)&gj[jj][dq] =
                *(const float4*)&g[(size_t)(b * NN + jc + jj) * NOUT + h * ND + dq];
        }
        // 2b: compute normalized p chunk (64 x 128), [j][i] layout
        #pragma unroll
        for (int k = 0; k < 8; ++k) {
            const int f  = t + 256 * k;      // 0..2047
            const int jj = f >> 5;
            const int iq = (f & 31) * 4;
            const float sdj = sd[jc + jj];
            float4 s4 = *(const float4*)&ss[iq];
            float4 m4 = *(const float4*)&mk[iq];
            float4 r4 = *(const float4*)&rr[iq];
            float4 p;
            float x;
            x = s4.x + sdj; x = fmaxf(x, 0.2f * x); p.x = exp2f(x * LOG2E - m4.x) * r4.x;
            x = s4.y + sdj; x = fmaxf(x, 0.2f * x); p.y = exp2f(x * LOG2E - m4.y) * r4.y;
            x = s4.z + sdj; x = fmaxf(x, 0.2f * x); p.z = exp2f(x * LOG2E - m4.z) * r4.z;
            x = s4.w + sdj; x = fmaxf(x, 0.2f * x); p.w = exp2f(x * LOG2E - m4.w) * r4.w;
            *(float4*)&pj[jj][iq] = p;
        }
        __syncthreads();

        // 2c: acc[i][d] += p[j][i] * g[j][d]
        #pragma unroll 8
        for (int jj = 0; jj < 64; ++jj) {
            float4 pv = *(const float4*)&pj[jj][ti * 4];
            float4 gv = *(const float4*)&gj[jj][td * 4];
            float pf[4] = {pv.x, pv.y, pv.z, pv.w};
            float gf[4] = {gv.x, gv.y, gv.z, gv.w};
            #pragma unroll
            for (int ii = 0; ii < 4; ++ii)
                #pragma unroll
                for (int dd = 0; dd < 4; ++dd)
                    acc[ii][dd] += pf[ii] * gf[dd];
        }
    }

    // ---- phase 3: write out ----
    #pragma unroll
    for (int ii = 0; ii < 4; ++ii) {
        const int i = i0 + ti * 4 + ii;
        float4 o;
        o.x = acc[ii][0]; o.y = acc[ii][1]; o.z = acc[ii][2]; o.w = acc[ii][3];
        *(float4*)&out[(size_t)(b * NN + i) * NOUT + h * ND + td * 4] = o;
    }
}

// ---------------------------------------------------------------------------
extern "C" void kernel_launch(void* const* d_in, const int* in_sizes, int n_in,
                              void* d_out, int out_size, void* d_ws, size_t ws_size,
                              hipStream_t stream) {
    (void)in_sizes; (void)n_in; (void)out_size; (void)ws_size;
    const float* vertex = (const float*)d_in[0];
    const float* w_vert = (const float*)d_in[1];
    const float* attn_w = (const float*)d_in[2];
    float* out = (float*)d_out;

    float* g     = (float*)d_ws;                       // 8192*256 floats (8 MB)
    float* s_src = g + (size_t)NROWS * NOUT;           // 64K floats
    float* s_dst = s_src + (size_t)NROWS * NH;         // 64K floats

    gat_gemm_kernel<<<dim3(4, 128), 256, 0, stream>>>(vertex, w_vert, attn_w,
                                                      g, s_src, s_dst);
    gat_attn_kernel<<<dim3(8, NH, NB), 256, 0, stream>>>(g, s_src, s_dst, out);
}